// Round 8
// baseline (228.124 us; speedup 1.0000x reference)
//
#include <hip/hip_runtime.h>
#include <hip/hip_bf16.h>

#define N_NODES 262144
#define N_GRAPHS 256
#define DMODEL 256
#define LOG2_F 0.69314718055994530942f

typedef __attribute__((ext_vector_type(4))) float f32x4;
typedef __attribute__((ext_vector_type(8))) short short8;

__device__ __forceinline__ short bf(float x) {
    __hip_bfloat16 h = __float2bfloat16(x);
    return __builtin_bit_cast(short, h);
}

__device__ __forceinline__ short8 cvt8(f32x4 lo, f32x4 hi) {
    short8 a;
    a[0] = bf(lo[0]); a[1] = bf(lo[1]); a[2] = bf(lo[2]); a[3] = bf(lo[3]);
    a[4] = bf(hi[0]); a[5] = bf(hi[1]); a[6] = bf(hi[2]); a[7] = bf(hi[3]);
    return a;
}

__device__ __forceinline__ void mfma8(short8 a, const char* bb, f32x4* acc) {
#pragma unroll
    for (int nt = 0; nt < 8; ++nt) {
        short8 bfrag = *reinterpret_cast<const short8*>(bb + nt * 1024);
        acc[nt] = __builtin_amdgcn_mfma_f32_16x16x32_bf16(a, bfrag, acc[nt], 0, 0, 0);
    }
}

// Pack g_enc (fp32 [G=256][D=256]) into bf16 B-fragments in MFMA lane order.
// chunk c = ks*16 + ntile (128 chunks of 1KB). Within chunk: lane*16B.
// B[k][g] = g_enc[g][k]; frag elem j of lane l: k = ks*32 + (l>>4)*8 + j,
// g = ntile*16 + (l&15).
__global__ void pack_b_kernel(const float* __restrict__ g_enc,
                              short* __restrict__ bout) {
    int b = blockIdx.x;        // 0..127
    int lane = threadIdx.x;    // 0..63
    int ks = b >> 4, nt = b & 15;
    int g = nt * 16 + (lane & 15);
    int k = ks * 32 + (lane >> 4) * 8;
    const float* src = g_enc + g * DMODEL + k;
    short8 v;
#pragma unroll
    for (int j = 0; j < 8; ++j) v[j] = bf(src[j]);
    reinterpret_cast<short8*>(bout)[b * 64 + lane] = v;
}

// Per wave-pass: 16 rows x 128 cols, acc[8] = 32 VGPRs.
// Waves 0-3: col-half 0; waves 4-7: col-half 1. Pass = 64 rows; 16 passes.
// A-loads: 4-deep NAMED register pipeline (b0..b3), software-pipelined
// across pass boundaries (subs 4-7 prefetch next pass's ks 0-3) so the
// vmem queue always holds ~8 loads -> counted vmcnt waits, never vmcnt(0).
// R7 was latency-bound at depth-1 (870 GB/s); this targets the HBM ceiling.
__global__ __launch_bounds__(512, 1) void mvgrl_main(
    const float* __restrict__ l_enc, const int* __restrict__ batch,
    const short* __restrict__ bpack, double* __restrict__ partials) {
    extern __shared__ char lds_raw[];  // 128KB: full B in fragment order

    const int tid = threadIdx.x;
    const int lane = tid & 63;
    const int wave = tid >> 6;   // 0..7
    const int wrow = wave & 3;   // row sub-stripe
    const int chalf = wave >> 2; // column half

    // ---- stage entire B (128KB) into LDS once ----
    {
        const short8* bp = reinterpret_cast<const short8*>(bpack);
        short8* lb = reinterpret_cast<short8*>(lds_raw);
#pragma unroll
        for (int c = 0; c < 16; ++c) {
            int chunk = wave + c * 8;
            lb[chunk * 64 + lane] = bp[chunk * 64 + lane];
        }
    }
    __syncthreads();
    // no further barriers until final reduction

    const int row_blk = blockIdx.x * 1024;
    const char* ldsB = lds_raw + chalf * 8192 + lane * 16;
    double dSall = 0.0, dSpq = 0.0, dSpr = 0.0;

    // A-pipeline registers (named; never runtime-indexed)
    f32x4 b0l, b0h, b1l, b1h, b2l, b2h, b3l, b3h;

    const float* arow = l_enc +
        (size_t)(row_blk + wrow * 16 + (lane & 15)) * DMODEL + (lane >> 4) * 8;
    b0l = *reinterpret_cast<const f32x4*>(arow + 0);
    b0h = *reinterpret_cast<const f32x4*>(arow + 4);
    b1l = *reinterpret_cast<const f32x4*>(arow + 32);
    b1h = *reinterpret_cast<const f32x4*>(arow + 36);
    b2l = *reinterpret_cast<const f32x4*>(arow + 64);
    b2h = *reinterpret_cast<const f32x4*>(arow + 68);
    b3l = *reinterpret_cast<const f32x4*>(arow + 96);
    b3h = *reinterpret_cast<const f32x4*>(arow + 100);

#pragma unroll 1
    for (int pass = 0; pass < 16; ++pass) {
        const int rowbase = row_blk + pass * 64 + wrow * 16;

        // batch values for this pass (issued early; drained for free by the
        // sub-4 vmcnt wait, since they're older than next-pass A loads)
        const int rsub = (lane >> 4) * 4;
        int bv0 = batch[rowbase + rsub + 0];
        int bv1 = batch[rowbase + rsub + 1];
        int bv2 = batch[rowbase + rsub + 2];
        int bv3 = batch[rowbase + rsub + 3];

        // next pass's A base ((pass+1)&15 wraps the last prefetch in-bounds)
        const int p2 = (pass + 1) & 15;
        const float* arow_next = l_enc +
            (size_t)(row_blk + p2 * 64 + wrow * 16 + (lane & 15)) * DMODEL +
            (lane >> 4) * 8;

        f32x4 acc[8];
#pragma unroll
        for (int n = 0; n < 8; ++n) acc[n] = (f32x4){0.f, 0.f, 0.f, 0.f};

        // subs 0-3: compute ks, refill with ks+4 of this pass
        {
            short8 a = cvt8(b0l, b0h);
            b0l = *reinterpret_cast<const f32x4*>(arow + 128);
            b0h = *reinterpret_cast<const f32x4*>(arow + 132);
            mfma8(a, ldsB + 0 * 16384, acc);
        }
        {
            short8 a = cvt8(b1l, b1h);
            b1l = *reinterpret_cast<const f32x4*>(arow + 160);
            b1h = *reinterpret_cast<const f32x4*>(arow + 164);
            mfma8(a, ldsB + 1 * 16384, acc);
        }
        {
            short8 a = cvt8(b2l, b2h);
            b2l = *reinterpret_cast<const f32x4*>(arow + 192);
            b2h = *reinterpret_cast<const f32x4*>(arow + 196);
            mfma8(a, ldsB + 2 * 16384, acc);
        }
        {
            short8 a = cvt8(b3l, b3h);
            b3l = *reinterpret_cast<const f32x4*>(arow + 224);
            b3h = *reinterpret_cast<const f32x4*>(arow + 228);
            mfma8(a, ldsB + 3 * 16384, acc);
        }
        // subs 4-7: compute ks, refill with NEXT pass's ks-4
        {
            short8 a = cvt8(b0l, b0h);
            b0l = *reinterpret_cast<const f32x4*>(arow_next + 0);
            b0h = *reinterpret_cast<const f32x4*>(arow_next + 4);
            mfma8(a, ldsB + 4 * 16384, acc);
        }
        {
            short8 a = cvt8(b1l, b1h);
            b1l = *reinterpret_cast<const f32x4*>(arow_next + 32);
            b1h = *reinterpret_cast<const f32x4*>(arow_next + 36);
            mfma8(a, ldsB + 5 * 16384, acc);
        }
        {
            short8 a = cvt8(b2l, b2h);
            b2l = *reinterpret_cast<const f32x4*>(arow_next + 64);
            b2h = *reinterpret_cast<const f32x4*>(arow_next + 68);
            mfma8(a, ldsB + 6 * 16384, acc);
        }
        {
            short8 a = cvt8(b3l, b3h);
            b3l = *reinterpret_cast<const f32x4*>(arow_next + 96);
            b3h = *reinterpret_cast<const f32x4*>(arow_next + 100);
            mfma8(a, ldsB + 7 * 16384, acc);
        }
        arow = arow_next;

        // ---- epilogue: q = softplus(r) - log2 ----
        // C/D layout: col = (chalf*8+nt)*16 + (lane&15),
        //             row = rowbase + (lane>>4)*4 + rg
        float Sall = 0.f, Spq = 0.f, Spr = 0.f;
        const int colbase = chalf * 128 + (lane & 15);
#pragma unroll
        for (int nt = 0; nt < 8; ++nt) {
            const int col = colbase + nt * 16;
            f32x4 av = acc[nt];
            {
                float r = av[0];
                float q = fmaxf(r, 0.f) - LOG2_F + __logf(1.f + __expf(-fabsf(r)));
                Sall += q; if (col == bv0) { Spq += q; Spr += r; }
            }
            {
                float r = av[1];
                float q = fmaxf(r, 0.f) - LOG2_F + __logf(1.f + __expf(-fabsf(r)));
                Sall += q; if (col == bv1) { Spq += q; Spr += r; }
            }
            {
                float r = av[2];
                float q = fmaxf(r, 0.f) - LOG2_F + __logf(1.f + __expf(-fabsf(r)));
                Sall += q; if (col == bv2) { Spq += q; Spr += r; }
            }
            {
                float r = av[3];
                float q = fmaxf(r, 0.f) - LOG2_F + __logf(1.f + __expf(-fabsf(r)));
                Sall += q; if (col == bv3) { Spq += q; Spr += r; }
            }
        }
        dSall += (double)Sall;
        dSpq += (double)Spq;
        dSpr += (double)Spr;
    }

    // ---- reduction: wave shuffle -> LDS -> block partial ----
#pragma unroll
    for (int off = 32; off; off >>= 1) {
        dSall += __shfl_xor(dSall, off);
        dSpq += __shfl_xor(dSpq, off);
        dSpr += __shfl_xor(dSpr, off);
    }
    __syncthreads();  // everyone done reading B before LDS reuse
    double* red = reinterpret_cast<double*>(lds_raw);
    if (lane == 0) {
        red[wave * 3 + 0] = dSall;
        red[wave * 3 + 1] = dSpq;
        red[wave * 3 + 2] = dSpr;
    }
    __syncthreads();
    if (tid == 0) {
        double a = 0, b = 0, c = 0;
#pragma unroll
        for (int w = 0; w < 8; ++w) {
            a += red[w * 3 + 0];
            b += red[w * 3 + 1];
            c += red[w * 3 + 2];
        }
        partials[blockIdx.x * 3 + 0] = a;
        partials[blockIdx.x * 3 + 1] = b;
        partials[blockIdx.x * 3 + 2] = c;
    }
}

__global__ void finalize_kernel(const double* __restrict__ p,
                                float* __restrict__ out) {
    int t = threadIdx.x;  // 256 threads, one partial-triple each
    double a = p[t * 3 + 0], b = p[t * 3 + 1], c = p[t * 3 + 2];
#pragma unroll
    for (int off = 32; off; off >>= 1) {
        a += __shfl_xor(a, off);
        b += __shfl_xor(b, off);
        c += __shfl_xor(c, off);
    }
    __shared__ double red[12];
    int lane = t & 63, w = t >> 6;
    if (lane == 0) { red[w * 3] = a; red[w * 3 + 1] = b; red[w * 3 + 2] = c; }
    __syncthreads();
    if (t == 0) {
        double A = 0, B = 0, C = 0;
#pragma unroll
        for (int i = 0; i < 4; ++i) {
            A += red[i * 3]; B += red[i * 3 + 1]; C += red[i * 3 + 2];
        }
        // neg_sum = S_all - S_posq ; pos_sum = S_posr - S_posq
        double neg = (A - B) / ((double)N_NODES * (double)(N_GRAPHS - 1));
        double pos = (C - B) / (double)N_NODES;
        out[0] = (float)(neg - pos);
    }
}

extern "C" void kernel_launch(void* const* d_in, const int* in_sizes, int n_in,
                              void* d_out, int out_size, void* d_ws,
                              size_t ws_size, hipStream_t stream) {
    const float* l_enc = (const float*)d_in[0];
    const float* g_enc = (const float*)d_in[1];
    const int* batch = (const int*)d_in[2];
    float* out = (float*)d_out;

    short* bpack = (short*)d_ws;                           // 128KB
    double* partials = (double*)((char*)d_ws + 131072);    // 256*3 doubles

    hipFuncSetAttribute(reinterpret_cast<const void*>(mvgrl_main),
                        hipFuncAttributeMaxDynamicSharedMemorySize, 131072);

    pack_b_kernel<<<128, 64, 0, stream>>>(g_enc, bpack);
    mvgrl_main<<<256, 512, 131072, stream>>>(l_enc, batch, bpack, partials);
    finalize_kernel<<<1, 256, 0, stream>>>(partials, out);
}

// Round 9
// 90.040 us; speedup vs baseline: 2.5336x; 2.5336x over previous
//
#include <hip/hip_runtime.h>
#include <hip/hip_bf16.h>

#define N_NODES 262144
#define N_GRAPHS 256
#define DMODEL 256
#define LOG2_F 0.69314718055994530942f

typedef __attribute__((ext_vector_type(4))) float f32x4;
typedef __attribute__((ext_vector_type(8))) short short8;

__device__ __forceinline__ short bf(float x) {
    __hip_bfloat16 h = __float2bfloat16(x);
    return __builtin_bit_cast(short, h);
}

__device__ __forceinline__ short8 cvt8(f32x4 lo, f32x4 hi) {
    short8 a;
    a[0] = bf(lo[0]); a[1] = bf(lo[1]); a[2] = bf(lo[2]); a[3] = bf(lo[3]);
    a[4] = bf(hi[0]); a[5] = bf(hi[1]); a[6] = bf(hi[2]); a[7] = bf(hi[3]);
    return a;
}

__device__ __forceinline__ void mfma8(short8 a, const char* bb, f32x4* acc) {
#pragma unroll
    for (int nt = 0; nt < 8; ++nt) {
        short8 bfrag = *reinterpret_cast<const short8*>(bb + nt * 1024);
        acc[nt] = __builtin_amdgcn_mfma_f32_16x16x32_bf16(a, bfrag, acc[nt], 0, 0, 0);
    }
}

// Pack g_enc (fp32 [G=256][D=256]) into bf16 B-fragments in MFMA lane order.
// chunk c = ks*16 + ntile (128 chunks of 1KB). Within chunk: lane*16B.
// B[k][g] = g_enc[g][k]; frag elem j of lane l: k = ks*32 + (l>>4)*8 + j,
// g = ntile*16 + (l&15).
__global__ void pack_b_kernel(const float* __restrict__ g_enc,
                              short* __restrict__ bout) {
    int b = blockIdx.x;        // 0..127
    int lane = threadIdx.x;    // 0..63
    int ks = b >> 4, nt = b & 15;
    int g = nt * 16 + (lane & 15);
    int k = ks * 32 + (lane >> 4) * 8;
    const float* src = g_enc + g * DMODEL + k;
    short8 v;
#pragma unroll
    for (int j = 0; j < 8; ++j) v[j] = bf(src[j]);
    reinterpret_cast<short8*>(bout)[b * 64 + lane] = v;
}

// Per wave-pass: 16 rows x 128 cols, acc[8] = 32 VGPRs.
// Waves 0-3: col-half 0; waves 4-7: col-half 1. Pass = 64 rows; 16 passes.
//
// A-pipeline at GROUP granularity: ks 0-7 split into 2 groups of 4. Four
// named slots (s0..s3, 32 VGPRs) hold the current group's fp32 data; while
// consuming group g we issue the 8 loads for group g+1 (g=1 loads the NEXT
// pass's group 0 -> no pass-start bubble; (pass+1)&15 keeps the final
// prefetch in-bounds). The `#pragma unroll 1` group loop keeps scheduling
// regions small so the compiler stays register-frugal (R7=48 VGPRs with
// this discipline; R8's fully-unrolled body hit the 128 cap and spilled).
__global__ __launch_bounds__(512, 1) void mvgrl_main(
    const float* __restrict__ l_enc, const int* __restrict__ batch,
    const short* __restrict__ bpack, double* __restrict__ partials) {
    extern __shared__ char lds_raw[];  // 128KB: full B in fragment order

    const int tid = threadIdx.x;
    const int lane = tid & 63;
    const int wave = tid >> 6;   // 0..7
    const int wrow = wave & 3;   // row sub-stripe
    const int chalf = wave >> 2; // column half

    // ---- stage entire B (128KB) into LDS once ----
    {
        const short8* bp = reinterpret_cast<const short8*>(bpack);
        short8* lb = reinterpret_cast<short8*>(lds_raw);
#pragma unroll
        for (int c = 0; c < 16; ++c) {
            int chunk = wave + c * 8;
            lb[chunk * 64 + lane] = bp[chunk * 64 + lane];
        }
    }
    __syncthreads();
    // no further barriers until final reduction

    const int row_blk = blockIdx.x * 1024;
    const char* ldsB = lds_raw + chalf * 8192 + lane * 16;
    double dSall = 0.0, dSpq = 0.0, dSpr = 0.0;

    // Named pipeline slots (never runtime-indexed)
    f32x4 s0l, s0h, s1l, s1h, s2l, s2h, s3l, s3h;

    const float* arow = l_enc +
        (size_t)(row_blk + wrow * 16 + (lane & 15)) * DMODEL + (lane >> 4) * 8;
    s0l = *reinterpret_cast<const f32x4*>(arow + 0);
    s0h = *reinterpret_cast<const f32x4*>(arow + 4);
    s1l = *reinterpret_cast<const f32x4*>(arow + 32);
    s1h = *reinterpret_cast<const f32x4*>(arow + 36);
    s2l = *reinterpret_cast<const f32x4*>(arow + 64);
    s2h = *reinterpret_cast<const f32x4*>(arow + 68);
    s3l = *reinterpret_cast<const f32x4*>(arow + 96);
    s3h = *reinterpret_cast<const f32x4*>(arow + 100);

#pragma unroll 1
    for (int pass = 0; pass < 16; ++pass) {
        const int rowbase = row_blk + pass * 64 + wrow * 16;
        const int rsub = (lane >> 4) * 4;
        int bv0 = batch[rowbase + rsub + 0];
        int bv1 = batch[rowbase + rsub + 1];
        int bv2 = batch[rowbase + rsub + 2];
        int bv3 = batch[rowbase + rsub + 3];

        const float* arow_next = l_enc +
            (size_t)(row_blk + ((pass + 1) & 15) * 64 + wrow * 16 + (lane & 15)) *
                DMODEL + (lane >> 4) * 8;

        f32x4 acc[8];
#pragma unroll
        for (int n = 0; n < 8; ++n) acc[n] = (f32x4){0.f, 0.f, 0.f, 0.f};

#pragma unroll 1
        for (int g = 0; g < 2; ++g) {
            // group g consumes slots (ks = g*4 .. g*4+3) and refills them
            // with: g==0 -> this pass ks 4..7; g==1 -> next pass ks 0..3.
            const float* src = (g == 0) ? (arow + 128) : arow_next;
            const char* lb = ldsB + (size_t)g * 4 * 16384;
            {
                short8 a = cvt8(s0l, s0h);
                s0l = *reinterpret_cast<const f32x4*>(src + 0);
                s0h = *reinterpret_cast<const f32x4*>(src + 4);
                mfma8(a, lb + 0 * 16384, acc);
            }
            {
                short8 a = cvt8(s1l, s1h);
                s1l = *reinterpret_cast<const f32x4*>(src + 32);
                s1h = *reinterpret_cast<const f32x4*>(src + 36);
                mfma8(a, lb + 1 * 16384, acc);
            }
            {
                short8 a = cvt8(s2l, s2h);
                s2l = *reinterpret_cast<const f32x4*>(src + 64);
                s2h = *reinterpret_cast<const f32x4*>(src + 68);
                mfma8(a, lb + 2 * 16384, acc);
            }
            {
                short8 a = cvt8(s3l, s3h);
                s3l = *reinterpret_cast<const f32x4*>(src + 96);
                s3h = *reinterpret_cast<const f32x4*>(src + 100);
                mfma8(a, lb + 3 * 16384, acc);
            }
        }
        arow = arow_next;

        // ---- epilogue: q = softplus(r) - log2 ----
        // C/D layout: col = (chalf*8+nt)*16 + (lane&15),
        //             row = rowbase + (lane>>4)*4 + rg
        float Sall = 0.f, Spq = 0.f, Spr = 0.f;
        const int colbase = chalf * 128 + (lane & 15);
#pragma unroll
        for (int nt = 0; nt < 8; ++nt) {
            const int col = colbase + nt * 16;
            f32x4 av = acc[nt];
            {
                float r = av[0];
                float q = fmaxf(r, 0.f) - LOG2_F + __logf(1.f + __expf(-fabsf(r)));
                Sall += q; if (col == bv0) { Spq += q; Spr += r; }
            }
            {
                float r = av[1];
                float q = fmaxf(r, 0.f) - LOG2_F + __logf(1.f + __expf(-fabsf(r)));
                Sall += q; if (col == bv1) { Spq += q; Spr += r; }
            }
            {
                float r = av[2];
                float q = fmaxf(r, 0.f) - LOG2_F + __logf(1.f + __expf(-fabsf(r)));
                Sall += q; if (col == bv2) { Spq += q; Spr += r; }
            }
            {
                float r = av[3];
                float q = fmaxf(r, 0.f) - LOG2_F + __logf(1.f + __expf(-fabsf(r)));
                Sall += q; if (col == bv3) { Spq += q; Spr += r; }
            }
        }
        dSall += (double)Sall;
        dSpq += (double)Spq;
        dSpr += (double)Spr;
    }

    // ---- reduction: wave shuffle -> LDS -> block partial ----
#pragma unroll
    for (int off = 32; off; off >>= 1) {
        dSall += __shfl_xor(dSall, off);
        dSpq += __shfl_xor(dSpq, off);
        dSpr += __shfl_xor(dSpr, off);
    }
    __syncthreads();  // everyone done reading B before LDS reuse
    double* red = reinterpret_cast<double*>(lds_raw);
    if (lane == 0) {
        red[wave * 3 + 0] = dSall;
        red[wave * 3 + 1] = dSpq;
        red[wave * 3 + 2] = dSpr;
    }
    __syncthreads();
    if (tid == 0) {
        double a = 0, b = 0, c = 0;
#pragma unroll
        for (int w = 0; w < 8; ++w) {
            a += red[w * 3 + 0];
            b += red[w * 3 + 1];
            c += red[w * 3 + 2];
        }
        partials[blockIdx.x * 3 + 0] = a;
        partials[blockIdx.x * 3 + 1] = b;
        partials[blockIdx.x * 3 + 2] = c;
    }
}

__global__ void finalize_kernel(const double* __restrict__ p,
                                float* __restrict__ out) {
    int t = threadIdx.x;  // 256 threads, one partial-triple each
    double a = p[t * 3 + 0], b = p[t * 3 + 1], c = p[t * 3 + 2];
#pragma unroll
    for (int off = 32; off; off >>= 1) {
        a += __shfl_xor(a, off);
        b += __shfl_xor(b, off);
        c += __shfl_xor(c, off);
    }
    __shared__ double red[12];
    int lane = t & 63, w = t >> 6;
    if (lane == 0) { red[w * 3] = a; red[w * 3 + 1] = b; red[w * 3 + 2] = c; }
    __syncthreads();
    if (t == 0) {
        double A = 0, B = 0, C = 0;
#pragma unroll
        for (int i = 0; i < 4; ++i) {
            A += red[i * 3]; B += red[i * 3 + 1]; C += red[i * 3 + 2];
        }
        // neg_sum = S_all - S_posq ; pos_sum = S_posr - S_posq
        double neg = (A - B) / ((double)N_NODES * (double)(N_GRAPHS - 1));
        double pos = (C - B) / (double)N_NODES;
        out[0] = (float)(neg - pos);
    }
}

extern "C" void kernel_launch(void* const* d_in, const int* in_sizes, int n_in,
                              void* d_out, int out_size, void* d_ws,
                              size_t ws_size, hipStream_t stream) {
    const float* l_enc = (const float*)d_in[0];
    const float* g_enc = (const float*)d_in[1];
    const int* batch = (const int*)d_in[2];
    float* out = (float*)d_out;

    short* bpack = (short*)d_ws;                           // 128KB
    double* partials = (double*)((char*)d_ws + 131072);    // 256*3 doubles

    hipFuncSetAttribute(reinterpret_cast<const void*>(mvgrl_main),
                        hipFuncAttributeMaxDynamicSharedMemorySize, 131072);

    pack_b_kernel<<<128, 64, 0, stream>>>(g_enc, bpack);
    mvgrl_main<<<256, 512, 131072, stream>>>(l_enc, batch, bpack, partials);
    finalize_kernel<<<1, 256, 0, stream>>>(partials, out);
}